// Round 1
// baseline (96.911 us; speedup 1.0000x reference)
//
#include <hip/hip_runtime.h>
#include <math.h>

#define NN 1024
#define DD 64

// One block per node. 256 threads = 4 waves.
// thread t: d4 = t & 15 (which float4 of the 64-dim feature), mo = t >> 4 (m stride lane).
// Main loop: per wave-iteration, 64 lanes read 1024 contiguous bytes of each neigh
// array (float4/lane) -> perfectly coalesced. adj[n,m] is broadcast across the 16
// lanes sharing m (one cacheline per 4 rows).
__global__ __launch_bounds__(256) void mean_agg_kernel(
    const float* __restrict__ adj,
    const float* __restrict__ nr,
    const float* __restrict__ ni,
    const float* __restrict__ sr,
    const float* __restrict__ si,
    const float* __restrict__ W,
    float* __restrict__ out)
{
    const int n  = blockIdx.x;
    const int t  = threadIdx.x;
    const int d4 = t & 15;   // float4 column group: covers d = d4*4 .. d4*4+3
    const int mo = t >> 4;   // m offset 0..15

    const float* __restrict__ nr_row  = nr  + (size_t)n * (NN * DD);
    const float* __restrict__ ni_row  = ni  + (size_t)n * (NN * DD);
    const float* __restrict__ adj_row = adj + (size_t)n * NN;

    float4 ar = make_float4(0.f, 0.f, 0.f, 0.f);
    float4 ai = make_float4(0.f, 0.f, 0.f, 0.f);
    float  dg = 0.f;

    #pragma unroll 4
    for (int m = mo; m < NN; m += 16) {
        const float a = adj_row[m];
        dg += a;
        const float4 vr = *reinterpret_cast<const float4*>(nr_row + m * DD + d4 * 4);
        const float4 vi = *reinterpret_cast<const float4*>(ni_row + m * DD + d4 * 4);
        ar.x = fmaf(a, vr.x, ar.x);
        ar.y = fmaf(a, vr.y, ar.y);
        ar.z = fmaf(a, vr.z, ar.z);
        ar.w = fmaf(a, vr.w, ar.w);
        ai.x = fmaf(a, vi.x, ai.x);
        ai.y = fmaf(a, vi.y, ai.y);
        ai.z = fmaf(a, vi.z, ai.z);
        ai.w = fmaf(a, vi.w, ai.w);
    }

    // Reduce across mo groups within each wave: lanes {l, l^16, l^32, l^48}
    // share the same d4 and together cover 4 of the 16 mo values.
    for (int off = 16; off < 64; off <<= 1) {
        ar.x += __shfl_xor(ar.x, off);
        ar.y += __shfl_xor(ar.y, off);
        ar.z += __shfl_xor(ar.z, off);
        ar.w += __shfl_xor(ar.w, off);
        ai.x += __shfl_xor(ai.x, off);
        ai.y += __shfl_xor(ai.y, off);
        ai.z += __shfl_xor(ai.z, off);
        ai.w += __shfl_xor(ai.w, off);
        dg   += __shfl_xor(dg,   off);
    }

    // Cross-wave reduction via LDS.
    __shared__ float lr[4][DD];     // per-wave partial sums (real)
    __shared__ float li[4][DD];     // per-wave partial sums (imag)
    __shared__ float ldg[4];        // per-wave deg partials
    __shared__ float mean_s[2][DD]; // finished means (real, imag)

    const int wv   = t >> 6;
    const int lane = t & 63;
    if (lane < 16) {
        *reinterpret_cast<float4*>(&lr[wv][lane * 4]) = ar;
        *reinterpret_cast<float4*>(&li[wv][lane * 4]) = ai;
        if (lane == 0) ldg[wv] = dg;
    }
    __syncthreads();

    if (t < 128) {
        const int part = t >> 6;      // 0 = real, 1 = imag
        const int d    = t & 63;
        const float* ls = part ? &li[0][0] : &lr[0][0];
        const float s   = ls[d] + ls[DD + d] + ls[2 * DD + d] + ls[3 * DD + d];
        const float deg = ldg[0] + ldg[1] + ldg[2] + ldg[3];
        float mean = s / deg;
        if (!isfinite(mean)) mean = 0.f;   // nan2zero + inf2zero
        mean_s[part][d] = mean;
    }
    __syncthreads();

    // from_neigh = mean @ W; out = relu(self + from_neigh).
    // Threads 0..63 -> real output column dq; 64..127 -> imag column dq.
    if (t < 128) {
        const int part = t >> 6;
        const int dq   = t & 63;
        const float* __restrict__ mv = mean_s[part];
        float acc = 0.f;
        #pragma unroll
        for (int d = 0; d < DD; ++d)
            acc = fmaf(mv[d], W[d * DD + dq], acc);   // mv[d] LDS broadcast, W coalesced
        const float* __restrict__ selfv = part ? si : sr;
        const float o = selfv[n * DD + dq] + acc;
        out[(size_t)part * (NN * DD) + n * DD + dq] = fmaxf(o, 0.f);
    }
}

extern "C" void kernel_launch(void* const* d_in, const int* in_sizes, int n_in,
                              void* d_out, int out_size, void* d_ws, size_t ws_size,
                              hipStream_t stream) {
    const float* adj = (const float*)d_in[0];
    const float* nr  = (const float*)d_in[1];
    const float* ni  = (const float*)d_in[2];
    const float* sr  = (const float*)d_in[3];
    const float* si  = (const float*)d_in[4];
    const float* W   = (const float*)d_in[5];
    float* out = (float*)d_out;

    mean_agg_kernel<<<dim3(NN), dim3(256), 0, stream>>>(adj, nr, ni, sr, si, W, out);
}

// Round 2
// 72.607 us; speedup vs baseline: 1.3347x; 1.3347x over previous
//
#include <hip/hip_runtime.h>
#include <math.h>

#define NN 1024
#define DD 64
#define TPB 512
#define MOG (TPB / 16)   // 32 m-groups

// One block per node. 512 threads = 8 waves -> 4 blocks/CU x 8 waves = 32 waves/CU.
// thread t: d4 = t & 15 (which float4 of the 64-dim feature), mo = t >> 4 (m group).
// adj is exactly {0,1}; the neigh loads are predicated on a != 0, so the exec
// mask suppresses the memory requests for zero groups (~half of all traffic).
__global__ __launch_bounds__(TPB) void mean_agg_kernel(
    const float* __restrict__ adj,
    const float* __restrict__ nr,
    const float* __restrict__ ni,
    const float* __restrict__ sr,
    const float* __restrict__ si,
    const float* __restrict__ W,
    float* __restrict__ out)
{
    const int n  = blockIdx.x;
    const int t  = threadIdx.x;
    const int d4 = t & 15;   // float4 column group: d = d4*4 .. d4*4+3
    const int mo = t >> 4;   // m offset 0..31

    const float* __restrict__ nr_row  = nr  + (size_t)n * (NN * DD);
    const float* __restrict__ ni_row  = ni  + (size_t)n * (NN * DD);
    const float* __restrict__ adj_row = adj + (size_t)n * NN;

    float4 ar = make_float4(0.f, 0.f, 0.f, 0.f);
    float4 ai = make_float4(0.f, 0.f, 0.f, 0.f);
    float  dg = 0.f;

    #pragma unroll 8
    for (int m = mo; m < NN; m += MOG) {
        const float a = adj_row[m];
        dg += a;
        if (a != 0.f) {   // group-uniform predicate: masked-off lanes fetch nothing
            const float4 vr = *reinterpret_cast<const float4*>(nr_row + m * DD + d4 * 4);
            const float4 vi = *reinterpret_cast<const float4*>(ni_row + m * DD + d4 * 4);
            ar.x = fmaf(a, vr.x, ar.x);
            ar.y = fmaf(a, vr.y, ar.y);
            ar.z = fmaf(a, vr.z, ar.z);
            ar.w = fmaf(a, vr.w, ar.w);
            ai.x = fmaf(a, vi.x, ai.x);
            ai.y = fmaf(a, vi.y, ai.y);
            ai.z = fmaf(a, vi.z, ai.z);
            ai.w = fmaf(a, vi.w, ai.w);
        }
    }

    // Within-wave reduction: lanes {l, l^16, l^32} share d4; wave covers 4 mo values.
    for (int off = 16; off < 64; off <<= 1) {
        ar.x += __shfl_xor(ar.x, off);
        ar.y += __shfl_xor(ar.y, off);
        ar.z += __shfl_xor(ar.z, off);
        ar.w += __shfl_xor(ar.w, off);
        ai.x += __shfl_xor(ai.x, off);
        ai.y += __shfl_xor(ai.y, off);
        ai.z += __shfl_xor(ai.z, off);
        ai.w += __shfl_xor(ai.w, off);
        dg   += __shfl_xor(dg,   off);
    }

    // Cross-wave reduction via LDS (8 waves).
    __shared__ float lr[8][DD];
    __shared__ float li[8][DD];
    __shared__ float ldg[8];
    __shared__ float mean_s[2][DD];

    const int wv   = t >> 6;
    const int lane = t & 63;
    if (lane < 16) {
        *reinterpret_cast<float4*>(&lr[wv][lane * 4]) = ar;
        *reinterpret_cast<float4*>(&li[wv][lane * 4]) = ai;
        if (lane == 0) ldg[wv] = dg;
    }
    __syncthreads();

    if (t < 128) {
        const int part = t >> 6;      // 0 = real, 1 = imag
        const int d    = t & 63;
        const float* ls = part ? &li[0][0] : &lr[0][0];
        float s = 0.f;
        #pragma unroll
        for (int w = 0; w < 8; ++w) s += ls[w * DD + d];
        const float deg = ldg[0] + ldg[1] + ldg[2] + ldg[3]
                        + ldg[4] + ldg[5] + ldg[6] + ldg[7];
        float mean = s / deg;
        if (!isfinite(mean)) mean = 0.f;   // nan2zero + inf2zero
        mean_s[part][d] = mean;
    }
    __syncthreads();

    // from_neigh = mean @ W; out = relu(self + from_neigh).
    if (t < 128) {
        const int part = t >> 6;
        const int dq   = t & 63;
        const float* __restrict__ mv = mean_s[part];
        float acc = 0.f;
        #pragma unroll
        for (int d = 0; d < DD; ++d)
            acc = fmaf(mv[d], W[d * DD + dq], acc);   // mv[d] LDS broadcast, W coalesced
        const float* __restrict__ selfv = part ? si : sr;
        const float o = selfv[n * DD + dq] + acc;
        out[(size_t)part * (NN * DD) + n * DD + dq] = fmaxf(o, 0.f);
    }
}

extern "C" void kernel_launch(void* const* d_in, const int* in_sizes, int n_in,
                              void* d_out, int out_size, void* d_ws, size_t ws_size,
                              hipStream_t stream) {
    const float* adj = (const float*)d_in[0];
    const float* nr  = (const float*)d_in[1];
    const float* ni  = (const float*)d_in[2];
    const float* sr  = (const float*)d_in[3];
    const float* si  = (const float*)d_in[4];
    const float* W   = (const float*)d_in[5];
    float* out = (float*)d_out;

    mean_agg_kernel<<<dim3(NN), dim3(TPB), 0, stream>>>(adj, nr, ni, sr, si, W, out);
}

// Round 3
// 47.832 us; speedup vs baseline: 2.0261x; 1.5179x over previous
//
#include <hip/hip_runtime.h>
#include <math.h>

#define NN 1024
#define DD 64
#define TPB 512

// One block per node, 512 threads = 8 waves.
// Phase 1: ballot-compact the nonzero entries of adj[n,:] into a sorted LDS
//          index list (deterministic, no atomics). deg = count.
// Phase 2: dense loop over live indices only; unconditional coalesced float4
//          loads (16 lanes x 16 B = one 256 B neigh row per group).
// Phase 3: shfl + LDS reduction, mean, 64x64 mat-vec vs W, add self, ReLU.
__global__ __launch_bounds__(TPB) void mean_agg_kernel(
    const float* __restrict__ adj,
    const float* __restrict__ nr,
    const float* __restrict__ ni,
    const float* __restrict__ sr,
    const float* __restrict__ si,
    const float* __restrict__ W,
    float* __restrict__ out)
{
    const int n    = blockIdx.x;
    const int t    = threadIdx.x;
    const int wv   = t >> 6;
    const int lane = t & 63;

    __shared__ int   idx[NN];       // compacted nonzero m indices (sorted)
    __shared__ int   wcnt[8];       // per-wave nonzero counts
    __shared__ float lr[8][DD];
    __shared__ float li[8][DD];
    __shared__ float mean_s[2][DD];

    const float* __restrict__ adj_row = adj + (size_t)n * NN;

    // ---- Phase 1: stream compaction of adj row (each wave owns 128 m's) ----
    const int   m0 = wv * 128 + lane;
    const int   m1 = m0 + 64;
    const float a0 = adj_row[m0];
    const float a1 = adj_row[m1];
    const unsigned long long mask0 = __ballot(a0 != 0.f);
    const unsigned long long mask1 = __ballot(a1 != 0.f);
    const int c0 = __popcll(mask0);
    const int c1 = __popcll(mask1);
    if (lane == 0) wcnt[wv] = c0 + c1;
    __syncthreads();

    int base = 0;
    #pragma unroll
    for (int w = 0; w < 8; ++w) if (w < wv) base += wcnt[w];
    int cnt = 0;
    #pragma unroll
    for (int w = 0; w < 8; ++w) cnt += wcnt[w];

    const unsigned long long lanemask = (lane == 63) ? 0x7fffffffffffffffULL
                                                     : ((1ULL << lane) - 1ULL);
    if (a0 != 0.f) idx[base + __popcll(mask0 & lanemask)] = m0;
    if (a1 != 0.f) idx[base + c0 + __popcll(mask1 & lanemask)] = m1;
    __syncthreads();

    // ---- Phase 2: dense accumulation over live neighbors ----
    const int d4 = t & 15;   // float4 column group
    const int mo = t >> 4;   // 0..31 (32 index-groups)

    const float* __restrict__ nr_row = nr + (size_t)n * (NN * DD);
    const float* __restrict__ ni_row = ni + (size_t)n * (NN * DD);

    float4 ar = make_float4(0.f, 0.f, 0.f, 0.f);
    float4 ai = make_float4(0.f, 0.f, 0.f, 0.f);

    #pragma unroll 4
    for (int k = mo; k < cnt; k += 32) {
        const int m = idx[k];                 // LDS broadcast within 16-lane group
        const float4 vr = *reinterpret_cast<const float4*>(nr_row + m * DD + d4 * 4);
        const float4 vi = *reinterpret_cast<const float4*>(ni_row + m * DD + d4 * 4);
        ar.x += vr.x; ar.y += vr.y; ar.z += vr.z; ar.w += vr.w;
        ai.x += vi.x; ai.y += vi.y; ai.z += vi.z; ai.w += vi.w;
    }

    // ---- Phase 3a: within-wave reduction (lanes sharing d4) ----
    for (int off = 16; off < 64; off <<= 1) {
        ar.x += __shfl_xor(ar.x, off);
        ar.y += __shfl_xor(ar.y, off);
        ar.z += __shfl_xor(ar.z, off);
        ar.w += __shfl_xor(ar.w, off);
        ai.x += __shfl_xor(ai.x, off);
        ai.y += __shfl_xor(ai.y, off);
        ai.z += __shfl_xor(ai.z, off);
        ai.w += __shfl_xor(ai.w, off);
    }

    if (lane < 16) {
        *reinterpret_cast<float4*>(&lr[wv][lane * 4]) = ar;
        *reinterpret_cast<float4*>(&li[wv][lane * 4]) = ai;
    }
    __syncthreads();

    // ---- Phase 3b: cross-wave reduce + mean (with non-finite -> 0) ----
    if (t < 128) {
        const int part = t >> 6;      // 0 = real, 1 = imag
        const int d    = t & 63;
        const float* ls = part ? &li[0][0] : &lr[0][0];
        float s = 0.f;
        #pragma unroll
        for (int w = 0; w < 8; ++w) s += ls[w * DD + d];
        const float deg = (float)cnt;
        float mean = s / deg;
        if (!isfinite(mean)) mean = 0.f;   // deg==0 -> 0, like nan2zero+inf2zero
        mean_s[part][d] = mean;
    }
    __syncthreads();

    // ---- Phase 3c: mean @ W, add self, ReLU ----
    if (t < 128) {
        const int part = t >> 6;
        const int dq   = t & 63;
        const float* __restrict__ mv = mean_s[part];
        float acc = 0.f;
        #pragma unroll
        for (int d = 0; d < DD; ++d)
            acc = fmaf(mv[d], W[d * DD + dq], acc);   // mv[d] broadcast, W coalesced
        const float* __restrict__ selfv = part ? si : sr;
        const float o = selfv[n * DD + dq] + acc;
        out[(size_t)part * (NN * DD) + n * DD + dq] = fmaxf(o, 0.f);
    }
}

extern "C" void kernel_launch(void* const* d_in, const int* in_sizes, int n_in,
                              void* d_out, int out_size, void* d_ws, size_t ws_size,
                              hipStream_t stream) {
    const float* adj = (const float*)d_in[0];
    const float* nr  = (const float*)d_in[1];
    const float* ni  = (const float*)d_in[2];
    const float* sr  = (const float*)d_in[3];
    const float* si  = (const float*)d_in[4];
    const float* W   = (const float*)d_in[5];
    float* out = (float*)d_out;

    mean_agg_kernel<<<dim3(NN), dim3(TPB), 0, stream>>>(adj, nr, ni, sr, si, W, out);
}